// Round 6
// baseline (537.058 us; speedup 1.0000x reference)
//
#include <hip/hip_runtime.h>

typedef unsigned int u32;
typedef __bf16 bf16x8 __attribute__((ext_vector_type(8)));
typedef _Float16 f16x8 __attribute__((ext_vector_type(8)));
typedef float f32x4 __attribute__((ext_vector_type(4)));

#define Tn 4
#define Bn 32
#define Cn 384
#define Nn 196
#define Hn 12
#define CNn (Cn*Nn)         // 75264
#define BCNn (Bn*CNn)       // 2408448
#define BHNn (Bn*Hn*Nn)     // 75264
#define PBITS (Tn*BHNn)     // 301056
#define TBCNn (Tn*BCNn)     // 9633792
#define NCOLS 6272          // B*N
#define WSZ 147456          // 384*384

// fp32 -> 3-way bf16 split (residual ~2^-24 rel)
__device__ __forceinline__ void split3(float v, __bf16& h, __bf16& m, __bf16& l) {
  h = (__bf16)v;  float r = v - (float)h;
  m = (__bf16)r;  float r2 = r - (float)m;
  l = (__bf16)r2;
}
// fp32 -> 2-way f16 split (residual ~2^-22 rel; subnormal flush adds <1e-7 abs)
__device__ __forceinline__ void split2h(float v, _Float16& h, _Float16& l) {
  h = (_Float16)v;  l = (_Float16)(v - (float)h);
}

// ---------------------------------------------------------------------------
// W split: QKV (p<3) -> iv-scaled f16 2-split wsp16[p][2][o][c];
// proj (p==3) -> iv-scaled bf16 3-split wspb[3][o][c]. shv[p][o] = BN shift.
// ---------------------------------------------------------------------------
struct WSplitArgs {
  const float* w[4]; const float* g[4]; const float* be[4];
  const float* mu[4]; const float* va[4]; const float* bias;
};
__global__ __launch_bounds__(256) void split_w(
    WSplitArgs a, _Float16* __restrict__ wsp16, __bf16* __restrict__ wspb,
    float* __restrict__ shv) {
  const int i = blockIdx.x * 256 + threadIdx.x;   // < 589824
  const int p = i / WSZ, r = i - p * WSZ;
  const int o = r / Cn;
  const float iv = a.g[p][o] / sqrtf(a.va[p][o] + 1e-5f);
  const float wv = a.w[p][r] * iv;
  if (p < 3) {
    _Float16 h, l;
    split2h(wv, h, l);
    wsp16[(size_t)(p * 2 + 0) * WSZ + r] = h;
    wsp16[(size_t)(p * 2 + 1) * WSZ + r] = l;
  } else {
    __bf16 h, m, l;
    split3(wv, h, m, l);
    wspb[(size_t)0 * WSZ + r] = h;
    wspb[(size_t)1 * WSZ + r] = m;
    wspb[(size_t)2 * WSZ + r] = l;
  }
  if (r - o * Cn == 0) {
    float sh = a.be[p][o] - a.mu[p][o] * iv;
    if (p == 3) sh += a.bias[o] * iv;
    shv[p * Cn + o] = sh;
  }
}

// ---------------------------------------------------------------------------
// x [t,b,c,n] -> xT [t][col=(b,n)][c] via LDS tile (both sides coalesced).
// Tile: 49 n x 128 c; LDS row stride 133 (bank stride 5 -> <=2-way).
// ---------------------------------------------------------------------------
__global__ __launch_bounds__(256) void transpose_x(
    const float* __restrict__ x, float* __restrict__ xT) {
  __shared__ float tile[49 * 133];
  const int t = blockIdx.x, b = blockIdx.y, ct = blockIdx.z;
  const int c0 = ct * 128;
  const int tid = threadIdx.x;
  for (int n0 = 0; n0 < Nn; n0 += 49) {
    // read: lanes fastest over n (coalesced 196B runs), scatter to LDS
    for (int idx = tid; idx < 49 * 128; idx += 256) {
      const int n = idx % 49, c = idx / 49;
      tile[n * 133 + c] = x[(size_t)t * BCNn + (size_t)b * CNn +
                            (size_t)(c0 + c) * Nn + n0 + n];
    }
    __syncthreads();
    // write: lanes fastest over c (coalesced 512B runs)
    for (int idx = tid; idx < 49 * 128; idx += 256) {
      const int c = idx % 128, n = idx / 128;
      xT[((size_t)t * NCOLS + (size_t)b * Nn + n0 + n) * Cn + c0 + c] =
          tile[n * 133 + c];
    }
    __syncthreads();
  }
}

// ---------------------------------------------------------------------------
// QKV GEMM, 3-product f16 2-split MFMA. Grid 1800 XCD-swizzled (R4 mapping):
// 9 (p,mt) variants of one (t,col) group adjacent on the same XCD.
// LDS XOR swizzle on 16B granules -> conflict-free (R4-proven).
// ---------------------------------------------------------------------------
__global__ __launch_bounds__(256, 3) void gemm_qkv_f16(
    const float* __restrict__ xT,       // [t][col][c] fp32
    const _Float16* __restrict__ wsp16, // [3][2][o][c] iv-scaled
    const float* __restrict__ shv,      // [4][o]
    float* __restrict__ yT)             // 3 contiguous [t][col][o]
{
  __shared__ _Float16 Asw[2][128][32];
  __shared__ _Float16 Bsw[2][128][32];
  const int bid = blockIdx.x;
  const int xcd = bid & 7, slot = bid >> 3;      // slot 0..224
  const int gl = slot / 9, v = slot - gl * 9;
  const int group = xcd * 25 + gl;               // 0..199
  if (group >= 196) return;
  const int colt = group % 49, t = group / 49;
  const int col0 = colt * 128;
  const int p = v / 3, mt = v - p * 3;
  const int o0 = mt * 128;
  const int tid = threadIdx.x, lane = tid & 63, wid = tid >> 6;
  const int wm = wid >> 1, wn = wid & 1;
  const int quad = lane >> 4, nl = lane & 15;
  const _Float16* Ag = wsp16 + (size_t)(p * 2) * WSZ;
  const float* Bg = xT + ((size_t)t * NCOLS + col0) * Cn;

  f32x4 acc[4][4] = {};

  for (int kk = 0; kk < 12; ++kk) {
    const int k0 = kk * 32;
    // global loads into regs (issue while prev MFMAs drain)
    f16x8 aval[4];
#pragma unroll
    for (int i = 0; i < 4; ++i) {
      const int u = tid + i * 256;          // < 1024
      const int s = u >> 9, rem = u & 511;
      const int row = rem >> 2, kb = rem & 3;
      aval[i] = *(const f16x8*)(Ag + (size_t)s * WSZ +
                                (size_t)(o0 + row) * Cn + k0 + kb * 8);
    }
    f32x4 bval[2][2];
#pragma unroll
    for (int i = 0; i < 2; ++i) {
      const int u = tid + i * 256;          // < 512
      const int row = u >> 2, kb = u & 3;
      const float* src = Bg + (size_t)row * Cn + k0 + kb * 8;
      bval[i][0] = *(const f32x4*)src;
      bval[i][1] = *(const f32x4*)(src + 4);
    }
    __syncthreads();   // prev frag reads done
#pragma unroll
    for (int i = 0; i < 4; ++i) {
      const int u = tid + i * 256;
      const int s = u >> 9, rem = u & 511;
      const int row = rem >> 2, kb = rem & 3;
      const int kbp = kb ^ ((row >> 1) & 3);
      *(f16x8*)&Asw[s][row][kbp * 8] = aval[i];
    }
#pragma unroll
    for (int i = 0; i < 2; ++i) {
      const int u = tid + i * 256;
      const int row = u >> 2, kb = u & 3;
      const int kbp = kb ^ ((row >> 1) & 3);
      _Float16 h8[8], l8[8];
#pragma unroll
      for (int j = 0; j < 8; ++j) {
        const float xv = (j < 4) ? bval[i][0][j] : bval[i][1][j - 4];
        split2h(xv, h8[j], l8[j]);
      }
      *(f16x8*)&Bsw[0][row][kbp * 8] = *(f16x8*)h8;
      *(f16x8*)&Bsw[1][row][kbp * 8] = *(f16x8*)l8;
    }
    __syncthreads();
    f16x8 af[2][4], bfr[2][4];
#pragma unroll
    for (int i = 0; i < 4; ++i) {
      const int ra = wm * 64 + i * 16 + nl;
      const int rb = wn * 64 + i * 16 + nl;
      const int ka = (quad ^ ((ra >> 1) & 3)) * 8;
      const int kb2 = (quad ^ ((rb >> 1) & 3)) * 8;
#pragma unroll
      for (int s = 0; s < 2; ++s) {
        af[s][i]  = *(const f16x8*)&Asw[s][ra][ka];
        bfr[s][i] = *(const f16x8*)&Bsw[s][rb][kb2];
      }
    }
#pragma unroll
    for (int mi = 0; mi < 4; ++mi)
#pragma unroll
      for (int ni = 0; ni < 4; ++ni) {
        f32x4 c = acc[mi][ni];
        c = __builtin_amdgcn_mfma_f32_16x16x32_f16(af[0][mi], bfr[0][ni], c, 0, 0, 0);
        c = __builtin_amdgcn_mfma_f32_16x16x32_f16(af[0][mi], bfr[1][ni], c, 0, 0, 0);
        c = __builtin_amdgcn_mfma_f32_16x16x32_f16(af[1][mi], bfr[0][ni], c, 0, 0, 0);
        acc[mi][ni] = c;
      }
  }
  // epilogue: + BN shift (iv folded into W), store yT[t][col][o]
  float* yTp = yT + (size_t)p * TBCNn;
#pragma unroll
  for (int mi = 0; mi < 4; ++mi) {
    const int ob = o0 + wm * 64 + mi * 16 + quad * 4;
    const f32x4 sh4 = *(const f32x4*)&shv[p * Cn + ob];
#pragma unroll
    for (int ni = 0; ni < 4; ++ni) {
      const int col = col0 + wn * 64 + ni * 16 + nl;
      f32x4 o4;
#pragma unroll
      for (int r = 0; r < 4; ++r) o4[r] = acc[mi][ni][r] + sh4[r];
      *(f32x4*)(yTp + ((size_t)t * NCOLS + col) * Cn + ob) = o4;
    }
  }
}

// ---------------------------------------------------------------------------
// LIF(th=1) + bitpack from yT layout (contiguous 128B reads per thread).
// ---------------------------------------------------------------------------
__global__ __launch_bounds__(256) void lif_pack3_T(
    const float* __restrict__ yTq, const float* __restrict__ yTk,
    const float* __restrict__ yTv, u32* __restrict__ bq,
    u32* __restrict__ bk, u32* __restrict__ bv) {
  const int p = blockIdx.x / 294;
  const int idx = (blockIdx.x - p * 294) * 256 + threadIdx.x;  // < 75264
  const float* yT = (p == 0) ? yTq : (p == 1) ? yTk : yTv;
  u32* bits = (p == 0) ? bq : (p == 1) ? bk : bv;
  const int h = idx % Hn, col = idx / Hn;
  const int b = col / Nn, n = col - b * Nn;
  float v[32];
#pragma unroll
  for (int d = 0; d < 32; ++d) v[d] = 0.f;
#pragma unroll
  for (int t = 0; t < Tn; ++t) {
    const f32x4* pp = (const f32x4*)(yT + ((size_t)t * NCOLS + col) * Cn + h * 32);
    u32 m = 0;
#pragma unroll
    for (int q = 0; q < 8; ++q) {
      f32x4 xx = pp[q];
#pragma unroll
      for (int r = 0; r < 4; ++r) {
        const int d = q * 4 + r;
        const float nv = v[d] + (xx[r] - v[d]) * 0.5f;
        const bool s = nv >= 1.0f;
        m |= (u32)(s ? 1u : 0u) << d;
        v[d] = s ? 0.f : nv;
      }
    }
    bits[(size_t)t * BHNn + ((size_t)b * Hn + h) * Nn + n] = m;
  }
}

// ---------------------------------------------------------------------------
// Attention + LIF(0.5) fused: one block per (b,h), t-loop inside (LIF state
// in regs), exact m-ascending fp32 sums (matches reference order), branchless
// inner loop (zero terms added exactly like the reference's full einsum).
// ---------------------------------------------------------------------------
__global__ __launch_bounds__(256) void attn_lif(
    const u32* __restrict__ qb, const u32* __restrict__ kb,
    const u32* __restrict__ vb, const float* __restrict__ policy,
    __bf16* __restrict__ sp) {
  __shared__ u32 qs[Nn], ks[Nn], vs[Nn];
  __shared__ float ps[Nn];
  __shared__ float vf[Nn * 32];
  const int b = blockIdx.x / Hn, h = blockIdx.x - b * Hn;
  const int tid = threadIdx.x;
  float v05[32];
#pragma unroll
  for (int d = 0; d < 32; ++d) v05[d] = 0.f;

  for (int t = 0; t < Tn; ++t) {
    const size_t boff = (size_t)t * BHNn + ((size_t)b * Hn + h) * Nn;
    for (int i = tid; i < Nn; i += 256) {
      qs[i] = qb[boff + i];
      ks[i] = kb[boff + i];
      vs[i] = vb[boff + i];
      ps[i] = policy[(size_t)(t * Bn + b) * Nn + i];
    }
    __syncthreads();
    for (int i = tid; i < Nn * 32; i += 256)
      vf[i] = (float)((vs[i >> 5] >> (i & 31)) & 1u);
    __syncthreads();
    if (tid < Nn) {
      const int n = tid;
      const u32 qn = qs[n];
      f32x4 acc[8] = {};
      for (int m = 0; m < Nn; ++m) {
        const float a = (float)__popc(qn & ks[m]);
        const float pm = ps[m];
        const float mask = (m == n) ? (pm + (1.0f - pm)) : pm;
        const float w = a * mask;
        const f32x4* vr = (const f32x4*)(vf + m * 32);
#pragma unroll
        for (int q = 0; q < 8; ++q) acc[q] += w * vr[q];
      }
      __bf16* op = sp + (size_t)t * BCNn + ((size_t)b * Nn + n) * Cn + h * 32;
#pragma unroll
      for (int q = 0; q < 4; ++q) {
        __bf16 s8[8];
#pragma unroll
        for (int r = 0; r < 8; ++r) {
          const int d = q * 8 + r;
          const float y = acc[d >> 2][d & 3] * 0.25f;
          const float nv = v05[d] + (y - v05[d]) * 0.5f;
          const bool s = nv >= 0.5f;
          s8[r] = (__bf16)(s ? 1.0f : 0.0f);
          v05[d] = s ? 0.f : nv;
        }
        *(bf16x8*)(op + q * 8) = *(bf16x8*)s8;
      }
    }
    __syncthreads();
  }
}

// ---------------------------------------------------------------------------
// proj GEMM: 3-split iv-scaled bf16 W x binary bf16 spikes (exact). XCD
// swizzle (600 blocks), prefetch-before-MFMA. z stored [t,b,o,n] (R4-proven,
// 16-lane coalesced dword stores).
// ---------------------------------------------------------------------------
__global__ __launch_bounds__(256, 3) void gemm_proj_mfma(
    const __bf16* __restrict__ sp, const __bf16* __restrict__ wspb,
    const float* __restrict__ shv, float* __restrict__ z)
{
  __shared__ __bf16 Asw[3][128][32];
  __shared__ __bf16 Bsw[128][32];
  const int bid = blockIdx.x;
  const int xcd = bid & 7, slot = bid >> 3;      // slot 0..74
  const int gl = slot / 3, mt = slot - gl * 3;
  const int group = xcd * 25 + gl;
  if (group >= 196) return;
  const int colt = group % 49, t = group / 49;
  const int col0 = colt * 128, o0 = mt * 128;
  const int tid = threadIdx.x, lane = tid & 63, wid = tid >> 6;
  const int wm = wid >> 1, wn = wid & 1;
  const int quad = lane >> 4, nl = lane & 15;
  const __bf16* Bg = sp + ((size_t)t * NCOLS + col0) * Cn;

  f32x4 acc[4][4] = {};
  bf16x8 aval[6], bval[2];
#pragma unroll
  for (int i = 0; i < 6; ++i) {
    const int u = tid + i * 256, s = u >> 9, rem = u & 511;
    const int row = rem >> 2, kb = rem & 3;
    aval[i] = *(const bf16x8*)(wspb + (size_t)s * WSZ + (size_t)(o0 + row) * Cn + kb * 8);
  }
#pragma unroll
  for (int i = 0; i < 2; ++i) {
    const int u = tid + i * 256, row = u >> 2, kb = u & 3;
    bval[i] = *(const bf16x8*)(Bg + (size_t)row * Cn + kb * 8);
  }

  for (int kk = 0; kk < 12; ++kk) {
    __syncthreads();
#pragma unroll
    for (int i = 0; i < 6; ++i) {
      const int u = tid + i * 256, s = u >> 9, rem = u & 511;
      const int row = rem >> 2, kb = rem & 3;
      const int kbp = kb ^ ((row >> 1) & 3);
      *(bf16x8*)&Asw[s][row][kbp * 8] = aval[i];
    }
#pragma unroll
    for (int i = 0; i < 2; ++i) {
      const int u = tid + i * 256, row = u >> 2, kb = u & 3;
      const int kbp = kb ^ ((row >> 1) & 3);
      *(bf16x8*)&Bsw[row][kbp * 8] = bval[i];
    }
    __syncthreads();
    if (kk < 11) {
      const int k0n = (kk + 1) * 32;
#pragma unroll
      for (int i = 0; i < 6; ++i) {
        const int u = tid + i * 256, s = u >> 9, rem = u & 511;
        const int row = rem >> 2, kb = rem & 3;
        aval[i] = *(const bf16x8*)(wspb + (size_t)s * WSZ +
                                   (size_t)(o0 + row) * Cn + k0n + kb * 8);
      }
#pragma unroll
      for (int i = 0; i < 2; ++i) {
        const int u = tid + i * 256, row = u >> 2, kb = u & 3;
        bval[i] = *(const bf16x8*)(Bg + (size_t)row * Cn + k0n + kb * 8);
      }
    }
    bf16x8 af[3][4], bfr[4];
#pragma unroll
    for (int i = 0; i < 4; ++i) {
      const int ra = wm * 64 + i * 16 + nl;
      const int rb = wn * 64 + i * 16 + nl;
      const int ka = (quad ^ ((ra >> 1) & 3)) * 8;
      const int kb2 = (quad ^ ((rb >> 1) & 3)) * 8;
      bfr[i] = *(const bf16x8*)&Bsw[rb][kb2];
#pragma unroll
      for (int s = 0; s < 3; ++s)
        af[s][i] = *(const bf16x8*)&Asw[s][ra][ka];
    }
#pragma unroll
    for (int mi = 0; mi < 4; ++mi)
#pragma unroll
      for (int ni = 0; ni < 4; ++ni) {
        f32x4 c = acc[mi][ni];
        c = __builtin_amdgcn_mfma_f32_16x16x32_bf16(af[0][mi], bfr[ni], c, 0, 0, 0);
        c = __builtin_amdgcn_mfma_f32_16x16x32_bf16(af[1][mi], bfr[ni], c, 0, 0, 0);
        c = __builtin_amdgcn_mfma_f32_16x16x32_bf16(af[2][mi], bfr[ni], c, 0, 0, 0);
        acc[mi][ni] = c;
      }
  }
#pragma unroll
  for (int mi = 0; mi < 4; ++mi) {
    const int ob = o0 + wm * 64 + mi * 16 + quad * 4;
    const f32x4 sh4 = *(const f32x4*)&shv[3 * Cn + ob];
#pragma unroll
    for (int ni = 0; ni < 4; ++ni) {
      const int col = col0 + wn * 64 + ni * 16 + nl;
      const int b = col / Nn, nn = col - b * Nn;
      float* zp = z + (size_t)t * BCNn + (size_t)b * CNn + nn;
#pragma unroll
      for (int r = 0; r < 4; ++r)
        zp[(size_t)(ob + r) * Nn] = acc[mi][ni][r] + sh4[r];
    }
  }
}

// final LIF(1.0): z [t,b,o,n] fp32 -> out binary fp32, float4 vectorized
__global__ __launch_bounds__(256) void lif_out_v4(
    const float* __restrict__ z, float* __restrict__ out) {
  const size_t i4 = ((size_t)blockIdx.x * 256 + threadIdx.x) * 4;
  f32x4 v = {0.f, 0.f, 0.f, 0.f};
#pragma unroll
  for (int t = 0; t < Tn; ++t) {
    f32x4 x = *(const f32x4*)(z + (size_t)t * BCNn + i4);
    f32x4 o4;
#pragma unroll
    for (int r = 0; r < 4; ++r) {
      const float nv = v[r] + (x[r] - v[r]) * 0.5f;
      const bool s = nv >= 1.0f;
      o4[r] = s ? 1.0f : 0.0f;
      v[r] = s ? 0.f : nv;
    }
    *(f32x4*)(out + (size_t)t * BCNn + i4) = o4;
  }
}

// ===========================================================================
extern "C" void kernel_launch(void* const* d_in, const int* in_sizes, int n_in,
                              void* d_out, int out_size, void* d_ws, size_t ws_size,
                              hipStream_t stream) {
  const float* x      = (const float*)d_in[0];
  const float* policy = (const float*)d_in[1];
  const float* qw = (const float*)d_in[2];
  const float* qg = (const float*)d_in[3];
  const float* qb_ = (const float*)d_in[4];
  const float* qm = (const float*)d_in[5];
  const float* qv = (const float*)d_in[6];
  const float* kw = (const float*)d_in[7];
  const float* kg = (const float*)d_in[8];
  const float* kbe = (const float*)d_in[9];
  const float* km = (const float*)d_in[10];
  const float* kv = (const float*)d_in[11];
  const float* vw = (const float*)d_in[12];
  const float* vg = (const float*)d_in[13];
  const float* vbe = (const float*)d_in[14];
  const float* vm = (const float*)d_in[15];
  const float* vv = (const float*)d_in[16];
  const float* pw = (const float*)d_in[17];
  const float* pg = (const float*)d_in[18];
  const float* pbe = (const float*)d_in[19];
  const float* pm = (const float*)d_in[20];
  const float* pv = (const float*)d_in[21];
  const float* pbias = (const float*)d_in[22];
  float* out = (float*)d_out;

  // workspace layout (bytes), total ~160.4 MB (harness provides >=161.2 MB,
  // proven by R3/R4 main paths)
  char* base = (char*)d_ws;
  float* xT      = (float*)base;                              // 38,535,168
  _Float16* wsp16 = (_Float16*)(base + (size_t)TBCNn * 4);    //  1,769,472
  __bf16* wspb   = (__bf16*)((char*)wsp16 + (size_t)6 * WSZ * 2); // 884,736
  float* shv     = (float*)((char*)wspb + (size_t)3 * WSZ * 2);   //   6,144
  float* yTq     = (float*)((char*)shv + 4 * Cn * 4);         // 38,535,168 x3
  float* yTk = yTq + TBCNn;
  float* yTv = yTk + TBCNn;
  u32* bq = (u32*)(yTv + TBCNn);                              //  3,612,672
  u32* bk = bq + PBITS;
  u32* bv = bk + PBITS;
  __bf16* sp = (__bf16*)yTk;   // alias: yTk dead after pack
  float* z   = yTv;            // alias: yTv dead after pack

  WSplitArgs wa;
  wa.w[0] = qw; wa.g[0] = qg; wa.be[0] = qb_; wa.mu[0] = qm; wa.va[0] = qv;
  wa.w[1] = kw; wa.g[1] = kg; wa.be[1] = kbe; wa.mu[1] = km; wa.va[1] = kv;
  wa.w[2] = vw; wa.g[2] = vg; wa.be[2] = vbe; wa.mu[2] = vm; wa.va[2] = vv;
  wa.w[3] = pw; wa.g[3] = pg; wa.be[3] = pbe; wa.mu[3] = pm; wa.va[3] = pv;
  wa.bias = pbias;
  split_w<<<2304, 256, 0, stream>>>(wa, wsp16, wspb, shv);
  transpose_x<<<dim3(4, 32, 3), 256, 0, stream>>>(x, xT);

  gemm_qkv_f16<<<1800, 256, 0, stream>>>(xT, wsp16, shv, yTq);
  lif_pack3_T<<<882, 256, 0, stream>>>(yTq, yTk, yTv, bq, bk, bv);
  attn_lif<<<Bn * Hn, 256, 0, stream>>>(bq, bk, bv, policy, sp);
  gemm_proj_mfma<<<600, 256, 0, stream>>>(sp, wspb, shv, z);
  lif_out_v4<<<BCNn / 1024, 256, 0, stream>>>(z, out);
}

// Round 7
// 413.300 us; speedup vs baseline: 1.2994x; 1.2994x over previous
//
#include <hip/hip_runtime.h>

typedef unsigned int u32;
typedef __bf16 bf16x8 __attribute__((ext_vector_type(8)));
typedef __bf16 bf16x4v __attribute__((ext_vector_type(4)));
typedef _Float16 f16x8 __attribute__((ext_vector_type(8)));
typedef float f32x4 __attribute__((ext_vector_type(4)));

#define Tn 4
#define Bn 32
#define Cn 384
#define Nn 196
#define Hn 12
#define CNn (Cn*Nn)         // 75264
#define BCNn (Bn*CNn)       // 2408448
#define BHNn (Bn*Hn*Nn)     // 75264
#define PBITS (Tn*BHNn)     // 301056
#define TBCNn (Tn*BCNn)     // 9633792
#define NCOLS 6272          // B*N
#define WSZ 147456          // 384*384

// fp32 -> 3-way bf16 split (residual ~2^-24 rel)
__device__ __forceinline__ void split3(float v, __bf16& h, __bf16& m, __bf16& l) {
  h = (__bf16)v;  float r = v - (float)h;
  m = (__bf16)r;  float r2 = r - (float)m;
  l = (__bf16)r2;
}
// fp32 -> 2-way f16 split (residual ~2^-22 rel)
__device__ __forceinline__ void split2h(float v, _Float16& h, _Float16& l) {
  h = (_Float16)v;  l = (_Float16)(v - (float)h);
}

// ---------------------------------------------------------------------------
// W split: QKV (p<3) -> iv-scaled f16 2-split; proj -> iv-scaled bf16 3-split.
// shv[p][o] = BN shift (+ bias*iv for proj).
// ---------------------------------------------------------------------------
struct WSplitArgs {
  const float* w[4]; const float* g[4]; const float* be[4];
  const float* mu[4]; const float* va[4]; const float* bias;
};
__global__ __launch_bounds__(256) void split_w(
    WSplitArgs a, _Float16* __restrict__ wsp16, __bf16* __restrict__ wspb,
    float* __restrict__ shv) {
  const int i = blockIdx.x * 256 + threadIdx.x;   // < 589824
  const int p = i / WSZ, r = i - p * WSZ;
  const int o = r / Cn;
  const float iv = a.g[p][o] / sqrtf(a.va[p][o] + 1e-5f);
  const float wv = a.w[p][r] * iv;
  if (p < 3) {
    _Float16 h, l;
    split2h(wv, h, l);
    wsp16[(size_t)(p * 2 + 0) * WSZ + r] = h;
    wsp16[(size_t)(p * 2 + 1) * WSZ + r] = l;
  } else {
    __bf16 h, m, l;
    split3(wv, h, m, l);
    wspb[(size_t)0 * WSZ + r] = h;
    wspb[(size_t)1 * WSZ + r] = m;
    wspb[(size_t)2 * WSZ + r] = l;
  }
  if (r - o * Cn == 0) {
    float sh = a.be[p][o] - a.mu[p][o] * iv;
    if (p == 3) sh += a.bias[o] * iv;
    shv[p * Cn + o] = sh;
  }
}

// ---------------------------------------------------------------------------
// x [t,b,c,n] -> xT [t][col=(b,n)][c] via LDS tile (both sides coalesced).
// ---------------------------------------------------------------------------
__global__ __launch_bounds__(256) void transpose_x(
    const float* __restrict__ x, float* __restrict__ xT) {
  __shared__ float tile[49 * 133];
  const int t = blockIdx.x, b = blockIdx.y, ct = blockIdx.z;
  const int c0 = ct * 128;
  const int tid = threadIdx.x;
  for (int n0 = 0; n0 < Nn; n0 += 49) {
    for (int idx = tid; idx < 49 * 128; idx += 256) {
      const int n = idx % 49, c = idx / 49;
      tile[n * 133 + c] = x[(size_t)t * BCNn + (size_t)b * CNn +
                            (size_t)(c0 + c) * Nn + n0 + n];
    }
    __syncthreads();
    for (int idx = tid; idx < 49 * 128; idx += 256) {
      const int c = idx % 128, n = idx / 128;
      xT[((size_t)t * NCOLS + (size_t)b * Nn + n0 + n) * Cn + c0 + c] =
          tile[n * 133 + c];
    }
    __syncthreads();
  }
}

// ---------------------------------------------------------------------------
// QKV GEMM, 3-product f16 2-split MFMA (R6-proven). Grid 1800 XCD-swizzled.
// ---------------------------------------------------------------------------
__global__ __launch_bounds__(256, 3) void gemm_qkv_f16(
    const float* __restrict__ xT,       // [t][col][c] fp32
    const _Float16* __restrict__ wsp16, // [3][2][o][c] iv-scaled
    const float* __restrict__ shv,      // [4][o]
    float* __restrict__ yT)             // 3 contiguous [t][col][o]
{
  __shared__ _Float16 Asw[2][128][32];
  __shared__ _Float16 Bsw[2][128][32];
  const int bid = blockIdx.x;
  const int xcd = bid & 7, slot = bid >> 3;      // slot 0..224
  const int gl = slot / 9, v = slot - gl * 9;
  const int group = xcd * 25 + gl;               // 0..199
  if (group >= 196) return;
  const int colt = group % 49, t = group / 49;
  const int col0 = colt * 128;
  const int p = v / 3, mt = v - p * 3;
  const int o0 = mt * 128;
  const int tid = threadIdx.x, lane = tid & 63, wid = tid >> 6;
  const int wm = wid >> 1, wn = wid & 1;
  const int quad = lane >> 4, nl = lane & 15;
  const _Float16* Ag = wsp16 + (size_t)(p * 2) * WSZ;
  const float* Bg = xT + ((size_t)t * NCOLS + col0) * Cn;

  f32x4 acc[4][4] = {};

  for (int kk = 0; kk < 12; ++kk) {
    const int k0 = kk * 32;
    f16x8 aval[4];
#pragma unroll
    for (int i = 0; i < 4; ++i) {
      const int u = tid + i * 256;
      const int s = u >> 9, rem = u & 511;
      const int row = rem >> 2, kb = rem & 3;
      aval[i] = *(const f16x8*)(Ag + (size_t)s * WSZ +
                                (size_t)(o0 + row) * Cn + k0 + kb * 8);
    }
    f32x4 bval[2][2];
#pragma unroll
    for (int i = 0; i < 2; ++i) {
      const int u = tid + i * 256;
      const int row = u >> 2, kb = u & 3;
      const float* src = Bg + (size_t)row * Cn + k0 + kb * 8;
      bval[i][0] = *(const f32x4*)src;
      bval[i][1] = *(const f32x4*)(src + 4);
    }
    __syncthreads();
#pragma unroll
    for (int i = 0; i < 4; ++i) {
      const int u = tid + i * 256;
      const int s = u >> 9, rem = u & 511;
      const int row = rem >> 2, kb = rem & 3;
      const int kbp = kb ^ ((row >> 1) & 3);
      *(f16x8*)&Asw[s][row][kbp * 8] = aval[i];
    }
#pragma unroll
    for (int i = 0; i < 2; ++i) {
      const int u = tid + i * 256;
      const int row = u >> 2, kb = u & 3;
      const int kbp = kb ^ ((row >> 1) & 3);
      _Float16 h8[8], l8[8];
#pragma unroll
      for (int j = 0; j < 8; ++j) {
        const float xv = (j < 4) ? bval[i][0][j] : bval[i][1][j - 4];
        split2h(xv, h8[j], l8[j]);
      }
      *(f16x8*)&Bsw[0][row][kbp * 8] = *(f16x8*)h8;
      *(f16x8*)&Bsw[1][row][kbp * 8] = *(f16x8*)l8;
    }
    __syncthreads();
    f16x8 af[2][4], bfr[2][4];
#pragma unroll
    for (int i = 0; i < 4; ++i) {
      const int ra = wm * 64 + i * 16 + nl;
      const int rb = wn * 64 + i * 16 + nl;
      const int ka = (quad ^ ((ra >> 1) & 3)) * 8;
      const int kb2 = (quad ^ ((rb >> 1) & 3)) * 8;
#pragma unroll
      for (int s = 0; s < 2; ++s) {
        af[s][i]  = *(const f16x8*)&Asw[s][ra][ka];
        bfr[s][i] = *(const f16x8*)&Bsw[s][rb][kb2];
      }
    }
#pragma unroll
    for (int mi = 0; mi < 4; ++mi)
#pragma unroll
      for (int ni = 0; ni < 4; ++ni) {
        f32x4 c = acc[mi][ni];
        c = __builtin_amdgcn_mfma_f32_16x16x32_f16(af[0][mi], bfr[0][ni], c, 0, 0, 0);
        c = __builtin_amdgcn_mfma_f32_16x16x32_f16(af[0][mi], bfr[1][ni], c, 0, 0, 0);
        c = __builtin_amdgcn_mfma_f32_16x16x32_f16(af[1][mi], bfr[0][ni], c, 0, 0, 0);
        acc[mi][ni] = c;
      }
  }
  float* yTp = yT + (size_t)p * TBCNn;
#pragma unroll
  for (int mi = 0; mi < 4; ++mi) {
    const int ob = o0 + wm * 64 + mi * 16 + quad * 4;
    const f32x4 sh4 = *(const f32x4*)&shv[p * Cn + ob];
#pragma unroll
    for (int ni = 0; ni < 4; ++ni) {
      const int col = col0 + wn * 64 + ni * 16 + nl;
      f32x4 o4;
#pragma unroll
      for (int r = 0; r < 4; ++r) o4[r] = acc[mi][ni][r] + sh4[r];
      *(f32x4*)(yTp + ((size_t)t * NCOLS + col) * Cn + ob) = o4;
    }
  }
}

// ---------------------------------------------------------------------------
// LIF(th=1) + bitpack from yT layout (contiguous 128B reads per thread).
// ---------------------------------------------------------------------------
__global__ __launch_bounds__(256) void lif_pack3_T(
    const float* __restrict__ yTq, const float* __restrict__ yTk,
    const float* __restrict__ yTv, u32* __restrict__ bq,
    u32* __restrict__ bk, u32* __restrict__ bv) {
  const int p = blockIdx.x / 294;
  const int idx = (blockIdx.x - p * 294) * 256 + threadIdx.x;  // < 75264
  const float* yT = (p == 0) ? yTq : (p == 1) ? yTk : yTv;
  u32* bits = (p == 0) ? bq : (p == 1) ? bk : bv;
  const int h = idx % Hn, col = idx / Hn;
  const int b = col / Nn, n = col - b * Nn;
  float v[32];
#pragma unroll
  for (int d = 0; d < 32; ++d) v[d] = 0.f;
#pragma unroll
  for (int t = 0; t < Tn; ++t) {
    const f32x4* pp = (const f32x4*)(yT + ((size_t)t * NCOLS + col) * Cn + h * 32);
    u32 m = 0;
#pragma unroll
    for (int q = 0; q < 8; ++q) {
      f32x4 xx = pp[q];
#pragma unroll
      for (int r = 0; r < 4; ++r) {
        const int d = q * 4 + r;
        const float nv = v[d] + (xx[r] - v[d]) * 0.5f;
        const bool s = nv >= 1.0f;
        m |= (u32)(s ? 1u : 0u) << d;
        v[d] = s ? 0.f : nv;
      }
    }
    bits[(size_t)t * BHNn + ((size_t)b * Hn + h) * Nn + n] = m;
  }
}

// ---------------------------------------------------------------------------
// Attention per (t,b,h), 4-row x 8-ch thread tile: V-reads broadcast across
// the 49 row-groups (free LDS), FMA:LDS ratio 4x R6. m-ascending fp32 sums
// (bit-identical to reference order). Writes y*0.25 fp32 -> yT[t][col][c].
// ---------------------------------------------------------------------------
__global__ __launch_bounds__(256) void attn_T4(
    const u32* __restrict__ qb, const u32* __restrict__ kb,
    const u32* __restrict__ vb, const float* __restrict__ policy,
    float* __restrict__ yT) {
  __shared__ u32 qs[Nn], ks[Nn], vs[Nn];
  __shared__ float ps[Nn];
  __shared__ float vf[Nn * 32];
  const int gid = blockIdx.x;          // (t*B+b)*H + h
  const int tb = gid / Hn;
  const int h = gid - tb * Hn;
  const int tid = threadIdx.x;
  for (int i = tid; i < Nn; i += 256) {
    qs[i] = qb[(size_t)gid * Nn + i];
    ks[i] = kb[(size_t)gid * Nn + i];
    vs[i] = vb[(size_t)gid * Nn + i];
    ps[i] = policy[(size_t)tb * Nn + i];
  }
  __syncthreads();
  for (int i = tid; i < Nn * 32; i += 256)
    vf[i] = (float)((vs[i >> 5] >> (i & 31)) & 1u);
  __syncthreads();
  if (tid < 196) {
    const int ng = tid % 49, cg = tid / 49;    // 49 row-groups x 4 ch-groups
    const int n0 = ng * 4;
    u32 qn[4];
#pragma unroll
    for (int j = 0; j < 4; ++j) qn[j] = qs[n0 + j];
    f32x4 acc[4][2] = {};
    for (int m = 0; m < Nn; ++m) {
      const u32 km = ks[m];
      const float pm = ps[m];
      const f32x4 v0 = *(const f32x4*)(vf + m * 32 + cg * 8);
      const f32x4 v1 = *(const f32x4*)(vf + m * 32 + cg * 8 + 4);
#pragma unroll
      for (int j = 0; j < 4; ++j) {
        const float a = (float)__popc(qn[j] & km);
        const float mask = (m == n0 + j) ? (pm + (1.0f - pm)) : pm;
        const float w = a * mask;
        acc[j][0] += w * v0;
        acc[j][1] += w * v1;
      }
    }
#pragma unroll
    for (int j = 0; j < 4; ++j) {
      float* op = yT + ((size_t)tb * Nn + n0 + j) * Cn + h * 32 + cg * 8;
      f32x4 o0, o1;
#pragma unroll
      for (int r = 0; r < 4; ++r) { o0[r] = acc[j][0][r] * 0.25f; o1[r] = acc[j][1][r] * 0.25f; }
      *(f32x4*)op = o0;
      *(f32x4*)(op + 4) = o1;
    }
  }
}

// LIF(0.5) over t on yT layout, emit spikes as exact bf16 -> sp[t][col][c]
__global__ __launch_bounds__(256) void lif05_bf16(
    const float* __restrict__ yT, __bf16* __restrict__ sp) {
  const size_t i4 = ((size_t)blockIdx.x * 256 + threadIdx.x) * 4;  // < BCN
  f32x4 v = {0.f, 0.f, 0.f, 0.f};
#pragma unroll
  for (int t = 0; t < Tn; ++t) {
    f32x4 x = *(const f32x4*)(yT + (size_t)t * BCNn + i4);
    __bf16 s4[4];
#pragma unroll
    for (int r = 0; r < 4; ++r) {
      const float nv = v[r] + (x[r] - v[r]) * 0.5f;
      const bool s = nv >= 0.5f;
      s4[r] = (__bf16)(s ? 1.0f : 0.0f);
      v[r] = s ? 0.f : nv;
    }
    *(bf16x4v*)(sp + (size_t)t * BCNn + i4) = *(bf16x4v*)s4;
  }
}

// ---------------------------------------------------------------------------
// proj GEMM: 3-split iv-scaled bf16 W x binary bf16 spikes (exact). XCD
// swizzle (600 blocks), prefetch-before-MFMA. z stored [t,b,o,n].
// ---------------------------------------------------------------------------
__global__ __launch_bounds__(256, 3) void gemm_proj_mfma(
    const __bf16* __restrict__ sp, const __bf16* __restrict__ wspb,
    const float* __restrict__ shv, float* __restrict__ z)
{
  __shared__ __bf16 Asw[3][128][32];
  __shared__ __bf16 Bsw[128][32];
  const int bid = blockIdx.x;
  const int xcd = bid & 7, slot = bid >> 3;      // slot 0..74
  const int gl = slot / 3, mt = slot - gl * 3;
  const int group = xcd * 25 + gl;
  if (group >= 196) return;
  const int colt = group % 49, t = group / 49;
  const int col0 = colt * 128, o0 = mt * 128;
  const int tid = threadIdx.x, lane = tid & 63, wid = tid >> 6;
  const int wm = wid >> 1, wn = wid & 1;
  const int quad = lane >> 4, nl = lane & 15;
  const __bf16* Bg = sp + ((size_t)t * NCOLS + col0) * Cn;

  f32x4 acc[4][4] = {};
  bf16x8 aval[6], bval[2];
#pragma unroll
  for (int i = 0; i < 6; ++i) {
    const int u = tid + i * 256, s = u >> 9, rem = u & 511;
    const int row = rem >> 2, kb = rem & 3;
    aval[i] = *(const bf16x8*)(wspb + (size_t)s * WSZ + (size_t)(o0 + row) * Cn + kb * 8);
  }
#pragma unroll
  for (int i = 0; i < 2; ++i) {
    const int u = tid + i * 256, row = u >> 2, kb = u & 3;
    bval[i] = *(const bf16x8*)(Bg + (size_t)row * Cn + kb * 8);
  }

  for (int kk = 0; kk < 12; ++kk) {
    __syncthreads();
#pragma unroll
    for (int i = 0; i < 6; ++i) {
      const int u = tid + i * 256, s = u >> 9, rem = u & 511;
      const int row = rem >> 2, kb = rem & 3;
      const int kbp = kb ^ ((row >> 1) & 3);
      *(bf16x8*)&Asw[s][row][kbp * 8] = aval[i];
    }
#pragma unroll
    for (int i = 0; i < 2; ++i) {
      const int u = tid + i * 256, row = u >> 2, kb = u & 3;
      const int kbp = kb ^ ((row >> 1) & 3);
      *(bf16x8*)&Bsw[row][kbp * 8] = bval[i];
    }
    __syncthreads();
    if (kk < 11) {
      const int k0n = (kk + 1) * 32;
#pragma unroll
      for (int i = 0; i < 6; ++i) {
        const int u = tid + i * 256, s = u >> 9, rem = u & 511;
        const int row = rem >> 2, kb = rem & 3;
        aval[i] = *(const bf16x8*)(wspb + (size_t)s * WSZ +
                                   (size_t)(o0 + row) * Cn + k0n + kb * 8);
      }
#pragma unroll
      for (int i = 0; i < 2; ++i) {
        const int u = tid + i * 256, row = u >> 2, kb = u & 3;
        bval[i] = *(const bf16x8*)(Bg + (size_t)row * Cn + k0n + kb * 8);
      }
    }
    bf16x8 af[3][4], bfr[4];
#pragma unroll
    for (int i = 0; i < 4; ++i) {
      const int ra = wm * 64 + i * 16 + nl;
      const int rb = wn * 64 + i * 16 + nl;
      const int ka = (quad ^ ((ra >> 1) & 3)) * 8;
      const int kb2 = (quad ^ ((rb >> 1) & 3)) * 8;
      bfr[i] = *(const bf16x8*)&Bsw[rb][kb2];
#pragma unroll
      for (int s = 0; s < 3; ++s)
        af[s][i] = *(const bf16x8*)&Asw[s][ra][ka];
    }
#pragma unroll
    for (int mi = 0; mi < 4; ++mi)
#pragma unroll
      for (int ni = 0; ni < 4; ++ni) {
        f32x4 c = acc[mi][ni];
        c = __builtin_amdgcn_mfma_f32_16x16x32_bf16(af[0][mi], bfr[ni], c, 0, 0, 0);
        c = __builtin_amdgcn_mfma_f32_16x16x32_bf16(af[1][mi], bfr[ni], c, 0, 0, 0);
        c = __builtin_amdgcn_mfma_f32_16x16x32_bf16(af[2][mi], bfr[ni], c, 0, 0, 0);
        acc[mi][ni] = c;
      }
  }
#pragma unroll
  for (int mi = 0; mi < 4; ++mi) {
    const int ob = o0 + wm * 64 + mi * 16 + quad * 4;
    const f32x4 sh4 = *(const f32x4*)&shv[3 * Cn + ob];
#pragma unroll
    for (int ni = 0; ni < 4; ++ni) {
      const int col = col0 + wn * 64 + ni * 16 + nl;
      const int b = col / Nn, nn = col - b * Nn;
      float* zp = z + (size_t)t * BCNn + (size_t)b * CNn + nn;
#pragma unroll
      for (int r = 0; r < 4; ++r)
        zp[(size_t)(ob + r) * Nn] = acc[mi][ni][r] + sh4[r];
    }
  }
}

// final LIF(1.0): z [t,b,o,n] fp32 -> out binary fp32, float4 vectorized
__global__ __launch_bounds__(256) void lif_out_v4(
    const float* __restrict__ z, float* __restrict__ out) {
  const size_t i4 = ((size_t)blockIdx.x * 256 + threadIdx.x) * 4;
  f32x4 v = {0.f, 0.f, 0.f, 0.f};
#pragma unroll
  for (int t = 0; t < Tn; ++t) {
    f32x4 x = *(const f32x4*)(z + (size_t)t * BCNn + i4);
    f32x4 o4;
#pragma unroll
    for (int r = 0; r < 4; ++r) {
      const float nv = v[r] + (x[r] - v[r]) * 0.5f;
      const bool s = nv >= 1.0f;
      o4[r] = s ? 1.0f : 0.0f;
      v[r] = s ? 0.f : nv;
    }
    *(f32x4*)(out + (size_t)t * BCNn + i4) = o4;
  }
}

// ===========================================================================
extern "C" void kernel_launch(void* const* d_in, const int* in_sizes, int n_in,
                              void* d_out, int out_size, void* d_ws, size_t ws_size,
                              hipStream_t stream) {
  const float* x      = (const float*)d_in[0];
  const float* policy = (const float*)d_in[1];
  const float* qw = (const float*)d_in[2];
  const float* qg = (const float*)d_in[3];
  const float* qb_ = (const float*)d_in[4];
  const float* qm = (const float*)d_in[5];
  const float* qv = (const float*)d_in[6];
  const float* kw = (const float*)d_in[7];
  const float* kg = (const float*)d_in[8];
  const float* kbe = (const float*)d_in[9];
  const float* km = (const float*)d_in[10];
  const float* kv = (const float*)d_in[11];
  const float* vw = (const float*)d_in[12];
  const float* vg = (const float*)d_in[13];
  const float* vbe = (const float*)d_in[14];
  const float* vm = (const float*)d_in[15];
  const float* vv = (const float*)d_in[16];
  const float* pw = (const float*)d_in[17];
  const float* pg = (const float*)d_in[18];
  const float* pbe = (const float*)d_in[19];
  const float* pm = (const float*)d_in[20];
  const float* pv = (const float*)d_in[21];
  const float* pbias = (const float*)d_in[22];
  float* out = (float*)d_out;

  // workspace layout (bytes), total ~160.4 MB
  char* base = (char*)d_ws;
  float* xT      = (float*)base;                              // 38,535,168
  _Float16* wsp16 = (_Float16*)(base + (size_t)TBCNn * 4);    //  1,769,472
  __bf16* wspb   = (__bf16*)((char*)wsp16 + (size_t)6 * WSZ * 2); // 884,736
  float* shv     = (float*)((char*)wspb + (size_t)3 * WSZ * 2);   //   6,144
  float* yTq     = (float*)((char*)shv + 4 * Cn * 4);         // 38,535,168 x3
  float* yTk = yTq + TBCNn;
  float* yTv = yTk + TBCNn;
  u32* bq = (u32*)(yTv + TBCNn);                              //  3,612,672
  u32* bk = bq + PBITS;
  u32* bv = bk + PBITS;
  __bf16* sp = (__bf16*)yTk;   // alias: yTk dead after pack
  float* z   = yTv;            // alias: yTv dead after pack

  WSplitArgs wa;
  wa.w[0] = qw; wa.g[0] = qg; wa.be[0] = qb_; wa.mu[0] = qm; wa.va[0] = qv;
  wa.w[1] = kw; wa.g[1] = kg; wa.be[1] = kbe; wa.mu[1] = km; wa.va[1] = kv;
  wa.w[2] = vw; wa.g[2] = vg; wa.be[2] = vbe; wa.mu[2] = vm; wa.va[2] = vv;
  wa.w[3] = pw; wa.g[3] = pg; wa.be[3] = pbe; wa.mu[3] = pm; wa.va[3] = pv;
  wa.bias = pbias;
  split_w<<<2304, 256, 0, stream>>>(wa, wsp16, wspb, shv);
  transpose_x<<<dim3(4, 32, 3), 256, 0, stream>>>(x, xT);

  gemm_qkv_f16<<<1800, 256, 0, stream>>>(xT, wsp16, shv, yTq);
  lif_pack3_T<<<882, 256, 0, stream>>>(yTq, yTk, yTv, bq, bk, bv);
  // attention (t-parallel) writes y*0.25 into yTq (dead after pack)
  attn_T4<<<Tn * Bn * Hn, 256, 0, stream>>>(bq, bk, bv, policy, yTq);
  lif05_bf16<<<BCNn / 1024, 256, 0, stream>>>(yTq, sp);
  gemm_proj_mfma<<<600, 256, 0, stream>>>(sp, wspb, shv, z);
  lif_out_v4<<<BCNn / 1024, 256, 0, stream>>>(z, out);
}

// Round 8
// 366.513 us; speedup vs baseline: 1.4653x; 1.1277x over previous
//
#include <hip/hip_runtime.h>

typedef unsigned int u32;
typedef __bf16 bf16x8 __attribute__((ext_vector_type(8)));
typedef __bf16 bf16x4v __attribute__((ext_vector_type(4)));
typedef _Float16 f16x8 __attribute__((ext_vector_type(8)));
typedef float f32x4 __attribute__((ext_vector_type(4)));

#define Tn 4
#define Bn 32
#define Cn 384
#define Nn 196
#define Hn 12
#define CNn (Cn*Nn)         // 75264
#define BCNn (Bn*CNn)       // 2408448
#define BHNn (Bn*Hn*Nn)     // 75264
#define PBITS (Tn*BHNn)     // 301056
#define TBCNn (Tn*BCNn)     // 9633792
#define NCOLS 6272          // B*N
#define WSZ 147456          // 384*384

// fp32 -> 3-way bf16 split (residual ~2^-24 rel)
__device__ __forceinline__ void split3(float v, __bf16& h, __bf16& m, __bf16& l) {
  h = (__bf16)v;  float r = v - (float)h;
  m = (__bf16)r;  float r2 = r - (float)m;
  l = (__bf16)r2;
}
// fp32 -> 2-way f16 split (residual ~2^-22 rel)
__device__ __forceinline__ void split2h(float v, _Float16& h, _Float16& l) {
  h = (_Float16)v;  l = (_Float16)(v - (float)h);
}

// ---------------------------------------------------------------------------
// W split: QKV (p<3) -> iv-scaled f16 2-split; proj -> iv-scaled bf16 3-split.
// ---------------------------------------------------------------------------
struct WSplitArgs {
  const float* w[4]; const float* g[4]; const float* be[4];
  const float* mu[4]; const float* va[4]; const float* bias;
};
__global__ __launch_bounds__(256) void split_w(
    WSplitArgs a, _Float16* __restrict__ wsp16, __bf16* __restrict__ wspb,
    float* __restrict__ shv) {
  const int i = blockIdx.x * 256 + threadIdx.x;   // < 589824
  const int p = i / WSZ, r = i - p * WSZ;
  const int o = r / Cn;
  const float iv = a.g[p][o] / sqrtf(a.va[p][o] + 1e-5f);
  const float wv = a.w[p][r] * iv;
  if (p < 3) {
    _Float16 h, l;
    split2h(wv, h, l);
    wsp16[(size_t)(p * 2 + 0) * WSZ + r] = h;
    wsp16[(size_t)(p * 2 + 1) * WSZ + r] = l;
  } else {
    __bf16 h, m, l;
    split3(wv, h, m, l);
    wspb[(size_t)0 * WSZ + r] = h;
    wspb[(size_t)1 * WSZ + r] = m;
    wspb[(size_t)2 * WSZ + r] = l;
  }
  if (r - o * Cn == 0) {
    float sh = a.be[p][o] - a.mu[p][o] * iv;
    if (p == 3) sh += a.bias[o] * iv;
    shv[p * Cn + o] = sh;
  }
}

// ---------------------------------------------------------------------------
// x [t,b,c,n] -> xT [t][col=(b,n)][c] via LDS tile.
// ---------------------------------------------------------------------------
__global__ __launch_bounds__(256) void transpose_x(
    const float* __restrict__ x, float* __restrict__ xT) {
  __shared__ float tile[49 * 133];
  const int t = blockIdx.x, b = blockIdx.y, ct = blockIdx.z;
  const int c0 = ct * 128;
  const int tid = threadIdx.x;
  for (int n0 = 0; n0 < Nn; n0 += 49) {
    for (int idx = tid; idx < 49 * 128; idx += 256) {
      const int n = idx % 49, c = idx / 49;
      tile[n * 133 + c] = x[(size_t)t * BCNn + (size_t)b * CNn +
                            (size_t)(c0 + c) * Nn + n0 + n];
    }
    __syncthreads();
    for (int idx = tid; idx < 49 * 128; idx += 256) {
      const int c = idx % 128, n = idx / 128;
      xT[((size_t)t * NCOLS + (size_t)b * Nn + n0 + n) * Cn + c0 + c] =
          tile[n * 133 + c];
    }
    __syncthreads();
  }
}

// ---------------------------------------------------------------------------
// QKV GEMM, 3-product f16 2-split MFMA (R6/R7-proven). Grid 1800 XCD-swizzled.
// ---------------------------------------------------------------------------
__global__ __launch_bounds__(256, 3) void gemm_qkv_f16(
    const float* __restrict__ xT,       // [t][col][c] fp32
    const _Float16* __restrict__ wsp16, // [3][2][o][c] iv-scaled
    const float* __restrict__ shv,      // [4][o]
    float* __restrict__ yT)             // 3 contiguous [t][col][o]
{
  __shared__ _Float16 Asw[2][128][32];
  __shared__ _Float16 Bsw[2][128][32];
  const int bid = blockIdx.x;
  const int xcd = bid & 7, slot = bid >> 3;      // slot 0..224
  const int gl = slot / 9, v = slot - gl * 9;
  const int group = xcd * 25 + gl;               // 0..199
  if (group >= 196) return;
  const int colt = group % 49, t = group / 49;
  const int col0 = colt * 128;
  const int p = v / 3, mt = v - p * 3;
  const int o0 = mt * 128;
  const int tid = threadIdx.x, lane = tid & 63, wid = tid >> 6;
  const int wm = wid >> 1, wn = wid & 1;
  const int quad = lane >> 4, nl = lane & 15;
  const _Float16* Ag = wsp16 + (size_t)(p * 2) * WSZ;
  const float* Bg = xT + ((size_t)t * NCOLS + col0) * Cn;

  f32x4 acc[4][4] = {};

  for (int kk = 0; kk < 12; ++kk) {
    const int k0 = kk * 32;
    f16x8 aval[4];
#pragma unroll
    for (int i = 0; i < 4; ++i) {
      const int u = tid + i * 256;
      const int s = u >> 9, rem = u & 511;
      const int row = rem >> 2, kb = rem & 3;
      aval[i] = *(const f16x8*)(Ag + (size_t)s * WSZ +
                                (size_t)(o0 + row) * Cn + k0 + kb * 8);
    }
    f32x4 bval[2][2];
#pragma unroll
    for (int i = 0; i < 2; ++i) {
      const int u = tid + i * 256;
      const int row = u >> 2, kb = u & 3;
      const float* src = Bg + (size_t)row * Cn + k0 + kb * 8;
      bval[i][0] = *(const f32x4*)src;
      bval[i][1] = *(const f32x4*)(src + 4);
    }
    __syncthreads();
#pragma unroll
    for (int i = 0; i < 4; ++i) {
      const int u = tid + i * 256;
      const int s = u >> 9, rem = u & 511;
      const int row = rem >> 2, kb = rem & 3;
      const int kbp = kb ^ ((row >> 1) & 3);
      *(f16x8*)&Asw[s][row][kbp * 8] = aval[i];
    }
#pragma unroll
    for (int i = 0; i < 2; ++i) {
      const int u = tid + i * 256;
      const int row = u >> 2, kb = u & 3;
      const int kbp = kb ^ ((row >> 1) & 3);
      _Float16 h8[8], l8[8];
#pragma unroll
      for (int j = 0; j < 8; ++j) {
        const float xv = (j < 4) ? bval[i][0][j] : bval[i][1][j - 4];
        split2h(xv, h8[j], l8[j]);
      }
      *(f16x8*)&Bsw[0][row][kbp * 8] = *(f16x8*)h8;
      *(f16x8*)&Bsw[1][row][kbp * 8] = *(f16x8*)l8;
    }
    __syncthreads();
    f16x8 af[2][4], bfr[2][4];
#pragma unroll
    for (int i = 0; i < 4; ++i) {
      const int ra = wm * 64 + i * 16 + nl;
      const int rb = wn * 64 + i * 16 + nl;
      const int ka = (quad ^ ((ra >> 1) & 3)) * 8;
      const int kb2 = (quad ^ ((rb >> 1) & 3)) * 8;
#pragma unroll
      for (int s = 0; s < 2; ++s) {
        af[s][i]  = *(const f16x8*)&Asw[s][ra][ka];
        bfr[s][i] = *(const f16x8*)&Bsw[s][rb][kb2];
      }
    }
#pragma unroll
    for (int mi = 0; mi < 4; ++mi)
#pragma unroll
      for (int ni = 0; ni < 4; ++ni) {
        f32x4 c = acc[mi][ni];
        c = __builtin_amdgcn_mfma_f32_16x16x32_f16(af[0][mi], bfr[0][ni], c, 0, 0, 0);
        c = __builtin_amdgcn_mfma_f32_16x16x32_f16(af[0][mi], bfr[1][ni], c, 0, 0, 0);
        c = __builtin_amdgcn_mfma_f32_16x16x32_f16(af[1][mi], bfr[0][ni], c, 0, 0, 0);
        acc[mi][ni] = c;
      }
  }
  float* yTp = yT + (size_t)p * TBCNn;
#pragma unroll
  for (int mi = 0; mi < 4; ++mi) {
    const int ob = o0 + wm * 64 + mi * 16 + quad * 4;
    const f32x4 sh4 = *(const f32x4*)&shv[p * Cn + ob];
#pragma unroll
    for (int ni = 0; ni < 4; ++ni) {
      const int col = col0 + wn * 64 + ni * 16 + nl;
      f32x4 o4;
#pragma unroll
      for (int r = 0; r < 4; ++r) o4[r] = acc[mi][ni][r] + sh4[r];
      *(f32x4*)(yTp + ((size_t)t * NCOLS + col) * Cn + ob) = o4;
    }
  }
}

// ---------------------------------------------------------------------------
// LIF(th=1) + bitpack from yT layout.
// ---------------------------------------------------------------------------
__global__ __launch_bounds__(256) void lif_pack3_T(
    const float* __restrict__ yTq, const float* __restrict__ yTk,
    const float* __restrict__ yTv, u32* __restrict__ bq,
    u32* __restrict__ bk, u32* __restrict__ bv) {
  const int p = blockIdx.x / 294;
  const int idx = (blockIdx.x - p * 294) * 256 + threadIdx.x;  // < 75264
  const float* yT = (p == 0) ? yTq : (p == 1) ? yTk : yTv;
  u32* bits = (p == 0) ? bq : (p == 1) ? bk : bv;
  const int h = idx % Hn, col = idx / Hn;
  const int b = col / Nn, n = col - b * Nn;
  float v[32];
#pragma unroll
  for (int d = 0; d < 32; ++d) v[d] = 0.f;
#pragma unroll
  for (int t = 0; t < Tn; ++t) {
    const f32x4* pp = (const f32x4*)(yT + ((size_t)t * NCOLS + col) * Cn + h * 32);
    u32 m = 0;
#pragma unroll
    for (int q = 0; q < 8; ++q) {
      f32x4 xx = pp[q];
#pragma unroll
      for (int r = 0; r < 4; ++r) {
        const int d = q * 4 + r;
        const float nv = v[d] + (xx[r] - v[d]) * 0.5f;
        const bool s = nv >= 1.0f;
        m |= (u32)(s ? 1u : 0u) << d;
        v[d] = s ? 0.f : nv;
      }
    }
    bits[(size_t)t * BHNn + ((size_t)b * Hn + h) * Nn + n] = m;
  }
}

// ---------------------------------------------------------------------------
// MFMA attention per (t,b,h): y = A·U + diag, where A[n,m]=popc(q&k) (exact
// bf16 int), U[m,d]=p_m*v[m,d] (exact fp32, 3-split bf16), diag adds
// a(n,n)*(1-p_n)*v[n,d]. M=n (13 tiles of 16, pad 208), K=m (7 slabs of 32,
// pad 224), N=d (2 tiles). LDS row stride 40 (16B-aligned, <=2-way banks).
// ---------------------------------------------------------------------------
#define ASTR 40
__global__ __launch_bounds__(256) void attn_mfma(
    const u32* __restrict__ qb, const u32* __restrict__ kb,
    const u32* __restrict__ vb, const float* __restrict__ policy,
    float* __restrict__ yT) {
  __shared__ u32 qs[208], ks[224], vs[224];
  __shared__ float ps[224];
  __shared__ __bf16 psp[3][224];
  __shared__ __bf16 Al[208 * ASTR];
  __shared__ __bf16 Ul[3][32 * ASTR];
  const int gid = blockIdx.x;          // (t*B+b)*H + h
  const int tb = gid / Hn;
  const int h = gid - tb * Hn;
  const int tid = threadIdx.x;
  const int lane = tid & 63, wid = tid >> 6;
  const int quad = lane >> 4, nl = lane & 15;

  // stage bits + policy (zero-padded)
  if (tid < 224) {
    const bool in = tid < Nn;
    qs[tid < 208 ? tid : 0] = 0;  // ensure init; real value below
  }
  for (int i = tid; i < 224; i += 256) {
    const bool in = i < Nn;
    if (i < 208) qs[i] = in ? qb[(size_t)gid * Nn + i] : 0u;
    ks[i] = in ? kb[(size_t)gid * Nn + i] : 0u;
    vs[i] = in ? vb[(size_t)gid * Nn + i] : 0u;
    const float p = in ? policy[(size_t)tb * Nn + i] : 0.f;
    ps[i] = p;
    __bf16 hh, mm, ll;
    split3(p, hh, mm, ll);
    psp[0][i] = hh; psp[1][i] = mm; psp[2][i] = ll;
  }
  __syncthreads();

  f32x4 acc[4][2] = {};   // up to 4 M-tiles x 2 N-tiles per wave

  for (int slab = 0; slab < 7; ++slab) {
    const int m0 = slab * 32;
    // build A-slab: thread = row n (208 used)
    if (tid < 208) {
      const u32 qn = qs[tid];
      __bf16 a32[32];
#pragma unroll
      for (int mk = 0; mk < 32; ++mk)
        a32[mk] = (__bf16)(float)__popc(qn & ks[m0 + mk]);
#pragma unroll
      for (int g = 0; g < 4; ++g)
        *(bf16x8*)&Al[tid * ASTR + g * 8] = *(bf16x8*)&a32[g * 8];
    }
    // build U-slab: thread -> (d', 4 mk)
    {
      const int dp = tid >> 3, mkg = (tid & 7) * 4;
      __bf16 u4[3][4];
#pragma unroll
      for (int j = 0; j < 4; ++j) {
        const int m = m0 + mkg + j;
        const bool bit = (vs[m] >> dp) & 1u;
#pragma unroll
        for (int s = 0; s < 3; ++s)
          u4[s][j] = bit ? psp[s][m] : (__bf16)0.f;
      }
#pragma unroll
      for (int s = 0; s < 3; ++s)
        *(bf16x4v*)&Ul[s][dp * ASTR + mkg] = *(bf16x4v*)u4[s];
    }
    __syncthreads();
    // MFMA: wave wid handles M-tiles {wid, wid+4, wid+8, wid+12<13}
    bf16x8 bfr[3][2];
#pragma unroll
    for (int s = 0; s < 3; ++s)
#pragma unroll
      for (int nt = 0; nt < 2; ++nt)
        bfr[s][nt] = *(const bf16x8*)&Ul[s][(nt * 16 + nl) * ASTR + quad * 8];
#pragma unroll
    for (int mi = 0; mi < 4; ++mi) {
      const int mt = wid + mi * 4;
      if (mt < 13) {
        const bf16x8 af = *(const bf16x8*)&Al[(mt * 16 + nl) * ASTR + quad * 8];
#pragma unroll
        for (int nt = 0; nt < 2; ++nt) {
          f32x4 c = acc[mi][nt];
          c = __builtin_amdgcn_mfma_f32_16x16x32_bf16(af, bfr[0][nt], c, 0, 0, 0);
          c = __builtin_amdgcn_mfma_f32_16x16x32_bf16(af, bfr[1][nt], c, 0, 0, 0);
          c = __builtin_amdgcn_mfma_f32_16x16x32_bf16(af, bfr[2][nt], c, 0, 0, 0);
          acc[mi][nt] = c;
        }
      }
    }
    __syncthreads();
  }
  // epilogue: diag correction + *0.25, store yT[tb*196+n][h*32+d]
#pragma unroll
  for (int mi = 0; mi < 4; ++mi) {
    const int mt = wid + mi * 4;
    if (mt >= 13) continue;
#pragma unroll
    for (int r = 0; r < 4; ++r) {
      const int n = mt * 16 + quad * 4 + r;
      if (n >= Nn) continue;
      const float ann = (float)__popc(qs[n] & ks[n]);
      const float wd = ann * (1.0f - ps[n]);
      const u32 vn = vs[n];
      float* op = yT + ((size_t)tb * Nn + n) * Cn + h * 32;
#pragma unroll
      for (int nt = 0; nt < 2; ++nt) {
        const int d = nt * 16 + nl;
        const float bit = (float)((vn >> d) & 1u);
        op[d] = (acc[mi][nt][r] + wd * bit) * 0.25f;
      }
    }
  }
}

// LIF(0.5) over t on yT layout, emit spikes as exact bf16 -> sp[t][col][c]
__global__ __launch_bounds__(256) void lif05_bf16(
    const float* __restrict__ yT, __bf16* __restrict__ sp) {
  const size_t i4 = ((size_t)blockIdx.x * 256 + threadIdx.x) * 4;  // < BCN
  f32x4 v = {0.f, 0.f, 0.f, 0.f};
#pragma unroll
  for (int t = 0; t < Tn; ++t) {
    f32x4 x = *(const f32x4*)(yT + (size_t)t * BCNn + i4);
    __bf16 s4[4];
#pragma unroll
    for (int r = 0; r < 4; ++r) {
      const float nv = v[r] + (x[r] - v[r]) * 0.5f;
      const bool s = nv >= 0.5f;
      s4[r] = (__bf16)(s ? 1.0f : 0.0f);
      v[r] = s ? 0.f : nv;
    }
    *(bf16x4v*)(sp + (size_t)t * BCNn + i4) = *(bf16x4v*)s4;
  }
}

// ---------------------------------------------------------------------------
// proj GEMM: 3-split iv-scaled bf16 W x binary bf16 spikes (exact).
// ---------------------------------------------------------------------------
__global__ __launch_bounds__(256, 3) void gemm_proj_mfma(
    const __bf16* __restrict__ sp, const __bf16* __restrict__ wspb,
    const float* __restrict__ shv, float* __restrict__ z)
{
  __shared__ __bf16 Asw[3][128][32];
  __shared__ __bf16 Bsw[128][32];
  const int bid = blockIdx.x;
  const int xcd = bid & 7, slot = bid >> 3;      // slot 0..74
  const int gl = slot / 3, mt = slot - gl * 3;
  const int group = xcd * 25 + gl;
  if (group >= 196) return;
  const int colt = group % 49, t = group / 49;
  const int col0 = colt * 128, o0 = mt * 128;
  const int tid = threadIdx.x, lane = tid & 63, wid = tid >> 6;
  const int wm = wid >> 1, wn = wid & 1;
  const int quad = lane >> 4, nl = lane & 15;
  const __bf16* Bg = sp + ((size_t)t * NCOLS + col0) * Cn;

  f32x4 acc[4][4] = {};
  bf16x8 aval[6], bval[2];
#pragma unroll
  for (int i = 0; i < 6; ++i) {
    const int u = tid + i * 256, s = u >> 9, rem = u & 511;
    const int row = rem >> 2, kb = rem & 3;
    aval[i] = *(const bf16x8*)(wspb + (size_t)s * WSZ + (size_t)(o0 + row) * Cn + kb * 8);
  }
#pragma unroll
  for (int i = 0; i < 2; ++i) {
    const int u = tid + i * 256, row = u >> 2, kb = u & 3;
    bval[i] = *(const bf16x8*)(Bg + (size_t)row * Cn + kb * 8);
  }

  for (int kk = 0; kk < 12; ++kk) {
    __syncthreads();
#pragma unroll
    for (int i = 0; i < 6; ++i) {
      const int u = tid + i * 256, s = u >> 9, rem = u & 511;
      const int row = rem >> 2, kb = rem & 3;
      const int kbp = kb ^ ((row >> 1) & 3);
      *(bf16x8*)&Asw[s][row][kbp * 8] = aval[i];
    }
#pragma unroll
    for (int i = 0; i < 2; ++i) {
      const int u = tid + i * 256, row = u >> 2, kb = u & 3;
      const int kbp = kb ^ ((row >> 1) & 3);
      *(bf16x8*)&Bsw[row][kbp * 8] = bval[i];
    }
    __syncthreads();
    if (kk < 11) {
      const int k0n = (kk + 1) * 32;
#pragma unroll
      for (int i = 0; i < 6; ++i) {
        const int u = tid + i * 256, s = u >> 9, rem = u & 511;
        const int row = rem >> 2, kb = rem & 3;
        aval[i] = *(const bf16x8*)(wspb + (size_t)s * WSZ +
                                   (size_t)(o0 + row) * Cn + k0n + kb * 8);
      }
#pragma unroll
      for (int i = 0; i < 2; ++i) {
        const int u = tid + i * 256, row = u >> 2, kb = u & 3;
        bval[i] = *(const bf16x8*)(Bg + (size_t)row * Cn + k0n + kb * 8);
      }
    }
    bf16x8 af[3][4], bfr[4];
#pragma unroll
    for (int i = 0; i < 4; ++i) {
      const int ra = wm * 64 + i * 16 + nl;
      const int rb = wn * 64 + i * 16 + nl;
      const int ka = (quad ^ ((ra >> 1) & 3)) * 8;
      const int kb2 = (quad ^ ((rb >> 1) & 3)) * 8;
      bfr[i] = *(const bf16x8*)&Bsw[rb][kb2];
#pragma unroll
      for (int s = 0; s < 3; ++s)
        af[s][i] = *(const bf16x8*)&Asw[s][ra][ka];
    }
#pragma unroll
    for (int mi = 0; mi < 4; ++mi)
#pragma unroll
      for (int ni = 0; ni < 4; ++ni) {
        f32x4 c = acc[mi][ni];
        c = __builtin_amdgcn_mfma_f32_16x16x32_bf16(af[0][mi], bfr[ni], c, 0, 0, 0);
        c = __builtin_amdgcn_mfma_f32_16x16x32_bf16(af[1][mi], bfr[ni], c, 0, 0, 0);
        c = __builtin_amdgcn_mfma_f32_16x16x32_bf16(af[2][mi], bfr[ni], c, 0, 0, 0);
        acc[mi][ni] = c;
      }
  }
#pragma unroll
  for (int mi = 0; mi < 4; ++mi) {
    const int ob = o0 + wm * 64 + mi * 16 + quad * 4;
    const f32x4 sh4 = *(const f32x4*)&shv[3 * Cn + ob];
#pragma unroll
    for (int ni = 0; ni < 4; ++ni) {
      const int col = col0 + wn * 64 + ni * 16 + nl;
      const int b = col / Nn, nn = col - b * Nn;
      float* zp = z + (size_t)t * BCNn + (size_t)b * CNn + nn;
#pragma unroll
      for (int r = 0; r < 4; ++r)
        zp[(size_t)(ob + r) * Nn] = acc[mi][ni][r] + sh4[r];
    }
  }
}

// final LIF(1.0): z [t,b,o,n] fp32 -> out binary fp32
__global__ __launch_bounds__(256) void lif_out_v4(
    const float* __restrict__ z, float* __restrict__ out) {
  const size_t i4 = ((size_t)blockIdx.x * 256 + threadIdx.x) * 4;
  f32x4 v = {0.f, 0.f, 0.f, 0.f};
#pragma unroll
  for (int t = 0; t < Tn; ++t) {
    f32x4 x = *(const f32x4*)(z + (size_t)t * BCNn + i4);
    f32x4 o4;
#pragma unroll
    for (int r = 0; r < 4; ++r) {
      const float nv = v[r] + (x[r] - v[r]) * 0.5f;
      const bool s = nv >= 1.0f;
      o4[r] = s ? 1.0f : 0.0f;
      v[r] = s ? 0.f : nv;
    }
    *(f32x4*)(out + (size_t)t * BCNn + i4) = o4;
  }
}

// ===========================================================================
extern "C" void kernel_launch(void* const* d_in, const int* in_sizes, int n_in,
                              void* d_out, int out_size, void* d_ws, size_t ws_size,
                              hipStream_t stream) {
  const float* x      = (const float*)d_in[0];
  const float* policy = (const float*)d_in[1];
  const float* qw = (const float*)d_in[2];
  const float* qg = (const float*)d_in[3];
  const float* qb_ = (const float*)d_in[4];
  const float* qm = (const float*)d_in[5];
  const float* qv = (const float*)d_in[6];
  const float* kw = (const float*)d_in[7];
  const float* kg = (const float*)d_in[8];
  const float* kbe = (const float*)d_in[9];
  const float* km = (const float*)d_in[10];
  const float* kv = (const float*)d_in[11];
  const float* vw = (const float*)d_in[12];
  const float* vg = (const float*)d_in[13];
  const float* vbe = (const float*)d_in[14];
  const float* vm = (const float*)d_in[15];
  const float* vv = (const float*)d_in[16];
  const float* pw = (const float*)d_in[17];
  const float* pg = (const float*)d_in[18];
  const float* pbe = (const float*)d_in[19];
  const float* pm = (const float*)d_in[20];
  const float* pv = (const float*)d_in[21];
  const float* pbias = (const float*)d_in[22];
  float* out = (float*)d_out;

  char* base = (char*)d_ws;
  float* xT      = (float*)base;                              // 38,535,168
  _Float16* wsp16 = (_Float16*)(base + (size_t)TBCNn * 4);    //  1,769,472
  __bf16* wspb   = (__bf16*)((char*)wsp16 + (size_t)6 * WSZ * 2); // 884,736
  float* shv     = (float*)((char*)wspb + (size_t)3 * WSZ * 2);   //   6,144
  float* yTq     = (float*)((char*)shv + 4 * Cn * 4);         // 38,535,168 x3
  float* yTk = yTq + TBCNn;
  float* yTv = yTk + TBCNn;
  u32* bq = (u32*)(yTv + TBCNn);                              //  3,612,672
  u32* bk = bq + PBITS;
  u32* bv = bk + PBITS;
  __bf16* sp = (__bf16*)yTk;   // alias: yTk dead after pack
  float* z   = yTv;            // alias: yTv dead after pack

  WSplitArgs wa;
  wa.w[0] = qw; wa.g[0] = qg; wa.be[0] = qb_; wa.mu[0] = qm; wa.va[0] = qv;
  wa.w[1] = kw; wa.g[1] = kg; wa.be[1] = kbe; wa.mu[1] = km; wa.va[1] = kv;
  wa.w[2] = vw; wa.g[2] = vg; wa.be[2] = vbe; wa.mu[2] = vm; wa.va[2] = vv;
  wa.w[3] = pw; wa.g[3] = pg; wa.be[3] = pbe; wa.mu[3] = pm; wa.va[3] = pv;
  wa.bias = pbias;
  split_w<<<2304, 256, 0, stream>>>(wa, wsp16, wspb, shv);
  transpose_x<<<dim3(4, 32, 3), 256, 0, stream>>>(x, xT);

  gemm_qkv_f16<<<1800, 256, 0, stream>>>(xT, wsp16, shv, yTq);
  lif_pack3_T<<<882, 256, 0, stream>>>(yTq, yTk, yTv, bq, bk, bv);
  // MFMA attention (t-parallel) writes y*0.25 into yTq (dead after pack)
  attn_mfma<<<Tn * Bn * Hn, 256, 0, stream>>>(bq, bk, bv, policy, yTq);
  lif05_bf16<<<BCNn / 1024, 256, 0, stream>>>(yTq, sp);
  gemm_proj_mfma<<<600, 256, 0, stream>>>(sp, wspb, shv, z);
  lif_out_v4<<<BCNn / 1024, 256, 0, stream>>>(z, out);
}